// Round 2
// baseline (64.448 us; speedup 1.0000x reference)
//
#include <hip/hip_runtime.h>
#include <hip/hip_bf16.h>
#include <math.h>

typedef _Float16 half8  __attribute__((ext_vector_type(8)));
typedef _Float16 half2v __attribute__((ext_vector_type(2)));
typedef __fp16   fp16x2 __attribute__((ext_vector_type(2)));
typedef float    f32x4  __attribute__((ext_vector_type(4)));

#define DDIM 128
#define LQ   512
#define NKV  2048
#define KVB  64
#define NCH  (NKV / KVB)

union U32H2 { unsigned u; fp16x2 h; };
union H8W   { unsigned u[4]; half8 h; };

__device__ __forceinline__ int swzv(int d) { return ((d ^ (d >> 4)) & 7) << 3; }

__global__ __launch_bounds__(256, 1)
void gattn(const float* __restrict__ seq, const float* __restrict__ fism,
           float* __restrict__ out)
{
  const int tid  = threadIdx.x;
  const int lane = tid & 63;
  const int wv   = tid >> 6;        // wave 0..3
  const int q16  = lane & 15;       // q row within wave tile (for stats / A-frag row)
  const int g    = lane >> 4;       // 4-lane-group 0..3
  const int b    = blockIdx.x >> 3;
  const int qb   = (blockIdx.x & 7) * 64;

  const float* seqB = seq  + (size_t)b * LQ * DDIM;
  const float* fisB = fism + (size_t)b * NKV * DDIM;
  float*       outB = out  + (size_t)b * LQ * DDIM;

  __shared__ _Float16 Ksh[KVB * DDIM];   // [64][128] f16, XOR-swizzled rows
  __shared__ _Float16 VTsh[DDIM * KVB];  // [128][64] f16 (V transposed), swizzled

  // ---- Q fragments (held for whole kernel) ----
  half8 qf[4];
  {
    const int qrow = qb + wv * 16 + q16;
    #pragma unroll
    for (int c = 0; c < 4; ++c) {
      const float* p = seqB + (size_t)qrow * DDIM + c * 32 + g * 8;
      float4 a  = *(const float4*)p;
      float4 b2 = *(const float4*)(p + 4);
      half8 h;
      h[0]=(_Float16)a.x;  h[1]=(_Float16)a.y;  h[2]=(_Float16)a.z;  h[3]=(_Float16)a.w;
      h[4]=(_Float16)b2.x; h[5]=(_Float16)b2.y; h[6]=(_Float16)b2.z; h[7]=(_Float16)b2.w;
      qf[c] = h;
    }
  }

  // staging assignment: thread covers rows {2sp, 2sp+1}, d in [16*dgrp, 16*dgrp+16)
  const int sp   = tid >> 3;   // 0..31
  const int dgrp = tid & 7;    // 0..7

  f32x4 acc[8];
  #pragma unroll
  for (int i = 0; i < 8; ++i) { f32x4 z = {0.f,0.f,0.f,0.f}; acc[i] = z; }

  float m_run = -INFINITY, tmax = -INFINITY, S_run = 0.f;

  auto write_stage = [&](const float4* v) {
    #pragma unroll
    for (int r = 0; r < 2; ++r) {
      const int row = 2*sp + r;
      #pragma unroll
      for (int hh = 0; hh < 2; ++hh) {
        const float4 x = v[r*4 + hh*2];
        const float4 y = v[r*4 + hh*2 + 1];
        half8 h;
        h[0]=(_Float16)x.x; h[1]=(_Float16)x.y; h[2]=(_Float16)x.z; h[3]=(_Float16)x.w;
        h[4]=(_Float16)y.x; h[5]=(_Float16)y.y; h[6]=(_Float16)y.z; h[7]=(_Float16)y.w;
        const int idx = row*DDIM + ((dgrp*16 + hh*8) ^ ((row & 7) << 3));
        *(half8*)&Ksh[idx] = h;
      }
    }
    #pragma unroll
    for (int k = 0; k < 16; ++k) {
      const int d = dgrp*16 + k;
      half2v pk;
      pk[0] = (_Float16)(((const float*)&v[k>>2])[k&3]);       // row 2sp
      pk[1] = (_Float16)(((const float*)&v[4 + (k>>2)])[k&3]); // row 2sp+1
      const int idx = d*KVB + ((2*sp) ^ swzv(d));
      *(half2v*)&VTsh[idx] = pk;
    }
  };

  // prologue: load + write chunk 0
  {
    float4 stg[8];
    #pragma unroll
    for (int r = 0; r < 2; ++r)
      #pragma unroll
      for (int k = 0; k < 4; ++k)
        stg[r*4+k] = *(const float4*)(fisB + (size_t)(2*sp + r)*DDIM + dgrp*16 + k*4);
    write_stage(stg);
  }

  for (int t = 0; t < NCH; ++t) {
    // issue next chunk's global loads early (overlap with compute)
    float4 nxt[8];
    const bool have = (t + 1 < NCH);
    if (have) {
      const float* src = fisB + (size_t)(t+1)*KVB*DDIM;
      #pragma unroll
      for (int r = 0; r < 2; ++r)
        #pragma unroll
        for (int k = 0; k < 4; ++k)
          nxt[r*4+k] = *(const float4*)(src + (size_t)(2*sp + r)*DDIM + dgrp*16 + k*4);
    }
    __syncthreads();   // LDS chunk t ready

    // ---- QK^T, swapped: S^T[n][q] = mfma(A=K, B=Q) ----
    f32x4 sv[4];
    #pragma unroll
    for (int ns = 0; ns < 4; ++ns) {
      f32x4 x = {0.f,0.f,0.f,0.f};
      const int row = ns*16 + q16;
      #pragma unroll
      for (int c = 0; c < 4; ++c) {
        const int idx = row*DDIM + ((c*32 + g*8) ^ ((row & 7) << 3));
        half8 kf = *(const half8*)&Ksh[idx];
        x = __builtin_amdgcn_mfma_f32_16x16x32_f16(kf, qf[c], x, 0, 0, 0);
      }
      sv[ns] = x;   // lane holds S[q=q16][n = t*64 + 16ns + 4g + i]
    }

    // ---- online power-softmax stats (exact-max tracked, rescale deferred) ----
    float cmax = sv[0][0];
    #pragma unroll
    for (int ns = 0; ns < 4; ++ns)
      #pragma unroll
      for (int i = 0; i < 4; ++i)
        cmax = fmaxf(cmax, sv[ns][i]);
    cmax = fmaxf(cmax, __shfl_xor(cmax, 16));
    cmax = fmaxf(cmax, __shfl_xor(cmax, 32));
    tmax = fmaxf(tmax, cmax);
    if (__any(cmax > m_run + 8.f)) {
      const float mn = fmaxf(m_run, cmax);
      const float sc = __expf(m_run - mn);   // 0 on first chunk (exp(-inf))
      S_run *= sc;
      m_run = mn;
      // broadcast per-output-row scales (output rows are 4g+i)
      const float s0 = __shfl(sc, (g<<4) | (4*g + 0));
      const float s1 = __shfl(sc, (g<<4) | (4*g + 1));
      const float s2 = __shfl(sc, (g<<4) | (4*g + 2));
      const float s3 = __shfl(sc, (g<<4) | (4*g + 3));
      const f32x4 scv = {s0, s1, s2, s3};
      #pragma unroll
      for (int dsu = 0; dsu < 8; ++dsu) acc[dsu] *= scv;
    }
    float lsum = 0.f;
    #pragma unroll
    for (int ns = 0; ns < 4; ++ns)
      #pragma unroll
      for (int i = 0; i < 4; ++i) {
        const float p = __expf(sv[ns][i] - m_run);  // bounded by e^8
        sv[ns][i] = p;
        lsum += p;
      }
    lsum += __shfl_xor(lsum, 16);
    lsum += __shfl_xor(lsum, 32);
    S_run += lsum;

    // ---- pack P to f16, redistribute to PV A-frag layout, PV MFMAs ----
    unsigned upk[4][2];
    #pragma unroll
    for (int ns = 0; ns < 4; ++ns) {
      U32H2 u0, u1;
      u0.h = __builtin_amdgcn_cvt_pkrtz(sv[ns][0], sv[ns][1]);
      u1.h = __builtin_amdgcn_cvt_pkrtz(sv[ns][2], sv[ns][3]);
      upk[ns][0] = u0.u; upk[ns][1] = u1.u;
    }
    #pragma unroll
    for (int c = 0; c < 2; ++c) {
      H8W aw;
      #pragma unroll
      for (int tt = 0; tt < 4; ++tt) {
        const int src = q16 + 16 * ((g & 1) * 2 + (tt >> 1));
        const unsigned lo = (unsigned)__shfl((int)upk[2*c  ][tt & 1], src);
        const unsigned hi = (unsigned)__shfl((int)upk[2*c+1][tt & 1], src);
        aw.u[tt] = (g < 2) ? lo : hi;
      }
      const half8 pa = aw.h;   // A[q=q16][n = c*32 + 8g + j]
      #pragma unroll
      for (int dsu = 0; dsu < 8; ++dsu) {
        const int d = dsu*16 + q16;
        const int idx = d*KVB + ((c*32 + g*8) ^ swzv(d));
        half8 vf = *(const half8*)&VTsh[idx];   // B[n][d]
        acc[dsu] = __builtin_amdgcn_mfma_f32_16x16x32_f16(pa, vf, acc[dsu], 0, 0, 0);
      }
    }

    __syncthreads();          // everyone done reading chunk t
    if (have) write_stage(nxt);
  }

  // ---- epilogue: exact power-softmax normalization + output fuse ----
  // att_vecs = (acc / sqrt(S_run)) * exp((m_run - true_max)/2)
  const float fs = __expf(0.5f * (m_run - tmax)) / sqrtf(S_run);
  float fsr[4];
  #pragma unroll
  for (int i = 0; i < 4; ++i)
    fsr[i] = __shfl(fs, (g<<4) | (4*g + i));
  #pragma unroll
  for (int dsu = 0; dsu < 8; ++dsu) {
    #pragma unroll
    for (int i = 0; i < 4; ++i) {
      const int qrow = qb + wv*16 + 4*g + i;
      const int d = dsu*16 + q16;
      const float s = seqB[(size_t)qrow * DDIM + d];
      outB[(size_t)qrow * DDIM + d] = 0.5f * s * (1.f + acc[dsu][i] * fsr[i]);
    }
  }
}

extern "C" void kernel_launch(void* const* d_in, const int* in_sizes, int n_in,
                              void* d_out, int out_size, void* d_ws, size_t ws_size,
                              hipStream_t stream) {
  const float* seq  = (const float*)d_in[0];
  const float* fism = (const float*)d_in[1];
  float* out = (float*)d_out;
  gattn<<<dim3(256), dim3(256), 0, stream>>>(seq, fism, out);
}

// Round 3
// 51.885 us; speedup vs baseline: 1.2421x; 1.2421x over previous
//
#include <hip/hip_runtime.h>
#include <hip/hip_bf16.h>
#include <math.h>

typedef _Float16 half8  __attribute__((ext_vector_type(8)));
typedef _Float16 half2v __attribute__((ext_vector_type(2)));
typedef __fp16   fp16x2 __attribute__((ext_vector_type(2)));
typedef float    f32x4  __attribute__((ext_vector_type(4)));

#define DDIM 128
#define LQ   512
#define NKV  2048
#define KVB  64
#define NPAIR (NKV / (2 * KVB))   // 16 chunk-pairs; each wave-half does 16 chunks

union U32H2 { unsigned u; fp16x2 h; };
union H8W   { unsigned u[4]; half8 h; };

__device__ __forceinline__ int swzv(int d) { return ((d ^ (d >> 4)) & 7) << 3; }

__global__ __launch_bounds__(512, 2)
void gattn(const float* __restrict__ seq, const float* __restrict__ fism,
           float* __restrict__ out)
{
  const int tid  = threadIdx.x;
  const int lane = tid & 63;
  const int wv   = tid >> 6;        // wave 0..7
  const int half = wv >> 2;         // KV-split half
  const int wq   = wv & 3;          // q-group 0..3
  const int q16  = lane & 15;
  const int g    = lane >> 4;

  // XCD swizzle: blocks of one batch co-resident on one XCD
  const int swz = (blockIdx.x & 7) * 32 + (blockIdx.x >> 3);
  const int b   = swz >> 3;
  const int qb  = (swz & 7) * 64;

  const float* seqB = seq  + (size_t)b * LQ * DDIM;
  const float* fisB = fism + (size_t)b * NKV * DDIM;
  float*       outB = out  + (size_t)b * LQ * DDIM;

  __shared__ _Float16 Ksh[2][KVB * DDIM];   // [buf][64][128] f16, XOR-swizzled
  __shared__ _Float16 VTsh[2][DDIM * KVB];  // [buf][128][64] f16 transposed, swizzled
  __shared__ float    stats[4][16][3];      // half1 partial {m, S, tmax}

  // ---- Q fragments ----
  half8 qf[4];
  {
    const int qrow = qb + wq * 16 + q16;
    #pragma unroll
    for (int c = 0; c < 4; ++c) {
      const float* p = seqB + (size_t)qrow * DDIM + c * 32 + g * 8;
      float4 a  = *(const float4*)p;
      float4 b2 = *(const float4*)(p + 4);
      half8 h;
      h[0]=(_Float16)a.x;  h[1]=(_Float16)a.y;  h[2]=(_Float16)a.z;  h[3]=(_Float16)a.w;
      h[4]=(_Float16)b2.x; h[5]=(_Float16)b2.y; h[6]=(_Float16)b2.z; h[7]=(_Float16)b2.w;
      qf[c] = h;
    }
  }

  // staging: 512 threads cover 128 rows (a chunk pair). sp=tid>>3 (0..63):
  // rows {2sp,2sp+1}; buffer = sp>>5; row-in-chunk = 2*(sp&31)+r. dgrp = 16 cols.
  const int sp   = tid >> 3;
  const int dgrp = tid & 7;
  const int bsel = sp >> 5;
  const int spc  = sp & 31;

  f32x4 acc[8];
  #pragma unroll
  for (int i = 0; i < 8; ++i) { f32x4 z = {0.f,0.f,0.f,0.f}; acc[i] = z; }

  float m_run = -INFINITY, tmax = -INFINITY, S_run = 0.f;

  auto write_stage = [&](const float4* v) {
    #pragma unroll
    for (int r = 0; r < 2; ++r) {
      const int row = 2*spc + r;
      #pragma unroll
      for (int hh = 0; hh < 2; ++hh) {
        const float4 x = v[r*4 + hh*2];
        const float4 y = v[r*4 + hh*2 + 1];
        half8 h;
        h[0]=(_Float16)x.x; h[1]=(_Float16)x.y; h[2]=(_Float16)x.z; h[3]=(_Float16)x.w;
        h[4]=(_Float16)y.x; h[5]=(_Float16)y.y; h[6]=(_Float16)y.z; h[7]=(_Float16)y.w;
        const int idx = row*DDIM + ((dgrp*16 + hh*8) ^ ((row & 7) << 3));
        *(half8*)&Ksh[bsel][idx] = h;
      }
    }
    #pragma unroll
    for (int k = 0; k < 16; ++k) {
      const int d = dgrp*16 + k;
      half2v pk;
      pk[0] = (_Float16)(((const float*)&v[k>>2])[k&3]);
      pk[1] = (_Float16)(((const float*)&v[4 + (k>>2)])[k&3]);
      const int idx = d*KVB + ((2*spc) ^ swzv(d));
      *(half2v*)&VTsh[bsel][idx] = pk;
    }
  };

  // prologue: stage pair 0
  {
    float4 stg[8];
    #pragma unroll
    for (int r = 0; r < 2; ++r)
      #pragma unroll
      for (int k = 0; k < 4; ++k)
        stg[r*4+k] = *(const float4*)(fisB + (size_t)(2*sp + r)*DDIM + dgrp*16 + k*4);
    write_stage(stg);
  }

  for (int tp = 0; tp < NPAIR; ++tp) {
    float4 nxt[8];
    const bool have = (tp + 1 < NPAIR);
    if (have) {
      const float* src = fisB + (size_t)(tp+1)*2*KVB*DDIM;
      #pragma unroll
      for (int r = 0; r < 2; ++r)
        #pragma unroll
        for (int k = 0; k < 4; ++k)
          nxt[r*4+k] = *(const float4*)(src + (size_t)(2*sp + r)*DDIM + dgrp*16 + k*4);
    }
    __syncthreads();   // pair tp staged

    // ---- QK^T on buf[half], swapped: lane holds S[q=q16][16ns+4g+i] ----
    f32x4 sv[4];
    #pragma unroll
    for (int ns = 0; ns < 4; ++ns) {
      f32x4 x = {0.f,0.f,0.f,0.f};
      const int row = ns*16 + q16;
      #pragma unroll
      for (int c = 0; c < 4; ++c) {
        const int idx = row*DDIM + ((c*32 + g*8) ^ ((row & 7) << 3));
        half8 kf = *(const half8*)&Ksh[half][idx];
        x = __builtin_amdgcn_mfma_f32_16x16x32_f16(kf, qf[c], x, 0, 0, 0);
      }
      sv[ns] = x;
    }

    // ---- online power-softmax stats ----
    float cmax = sv[0][0];
    #pragma unroll
    for (int ns = 0; ns < 4; ++ns)
      #pragma unroll
      for (int i = 0; i < 4; ++i)
        cmax = fmaxf(cmax, sv[ns][i]);
    cmax = fmaxf(cmax, __shfl_xor(cmax, 16));
    cmax = fmaxf(cmax, __shfl_xor(cmax, 32));
    tmax = fmaxf(tmax, cmax);
    if (__any(cmax > m_run + 8.f)) {
      const float mn = fmaxf(m_run, cmax);
      const float sc = __expf(m_run - mn);
      S_run *= sc;
      m_run = mn;
      const float s0 = __shfl(sc, (g<<4) | (4*g + 0));
      const float s1 = __shfl(sc, (g<<4) | (4*g + 1));
      const float s2 = __shfl(sc, (g<<4) | (4*g + 2));
      const float s3 = __shfl(sc, (g<<4) | (4*g + 3));
      const f32x4 scv = {s0, s1, s2, s3};
      #pragma unroll
      for (int dsu = 0; dsu < 8; ++dsu) acc[dsu] *= scv;
    }
    float lsum = 0.f;
    #pragma unroll
    for (int ns = 0; ns < 4; ++ns)
      #pragma unroll
      for (int i = 0; i < 4; ++i) {
        const float p = __expf(sv[ns][i] - m_run);
        sv[ns][i] = p;
        lsum += p;
      }
    lsum += __shfl_xor(lsum, 16);
    lsum += __shfl_xor(lsum, 32);
    S_run += lsum;

    // ---- P->f16, redistribute to PV A-frag, PV MFMAs on buf[half] ----
    unsigned upk[4][2];
    #pragma unroll
    for (int ns = 0; ns < 4; ++ns) {
      U32H2 u0, u1;
      u0.h = __builtin_amdgcn_cvt_pkrtz(sv[ns][0], sv[ns][1]);
      u1.h = __builtin_amdgcn_cvt_pkrtz(sv[ns][2], sv[ns][3]);
      upk[ns][0] = u0.u; upk[ns][1] = u1.u;
    }
    #pragma unroll
    for (int c = 0; c < 2; ++c) {
      H8W aw;
      #pragma unroll
      for (int tt = 0; tt < 4; ++tt) {
        const int src = q16 + 16 * ((g & 1) * 2 + (tt >> 1));
        const unsigned lo = (unsigned)__shfl((int)upk[2*c  ][tt & 1], src);
        const unsigned hi = (unsigned)__shfl((int)upk[2*c+1][tt & 1], src);
        aw.u[tt] = (g < 2) ? lo : hi;
      }
      const half8 pa = aw.h;
      #pragma unroll
      for (int dsu = 0; dsu < 8; ++dsu) {
        const int d = dsu*16 + q16;
        const int idx = d*KVB + ((c*32 + g*8) ^ swzv(d));
        half8 vf = *(const half8*)&VTsh[half][idx];
        acc[dsu] = __builtin_amdgcn_mfma_f32_16x16x32_f16(pa, vf, acc[dsu], 0, 0, 0);
      }
    }

    __syncthreads();
    if (have) write_stage(nxt);
  }

  // ---- combine halves: half1 spills partials via LDS (reusing buf1) ----
  if (half == 1) {
    float* d0 = (float*)&Ksh[1][0];   // acc[0..3]: 4 waves x 64 lanes x 16 f
    float* d1 = (float*)&VTsh[1][0];  // acc[4..7]
    const int base = (wq*64 + lane) * 16;
    #pragma unroll
    for (int dsu = 0; dsu < 4; ++dsu) {
      *(f32x4*)&d0[base + dsu*4] = acc[dsu];
      *(f32x4*)&d1[base + dsu*4] = acc[dsu + 4];
    }
    if (g == 0) {
      stats[wq][q16][0] = m_run;
      stats[wq][q16][1] = S_run;
      stats[wq][q16][2] = tmax;
    }
  }
  __syncthreads();

  if (half == 0) {
    const float m1 = stats[wq][q16][0];
    const float S1 = stats[wq][q16][1];
    const float t1 = stats[wq][q16][2];
    const float M  = fmaxf(tmax, t1);
    const float a0 = __expf(m_run - M);
    const float a1 = __expf(m1 - M);
    const float rs = rsqrtf(a0 * S_run + a1 * S1);
    const float f0 = a0 * rs, f1 = a1 * rs;
    float f0r[4], f1r[4];
    #pragma unroll
    for (int i = 0; i < 4; ++i) {
      const int src = (g<<4) | (4*g + i);
      f0r[i] = __shfl(f0, src);
      f1r[i] = __shfl(f1, src);
    }
    const float* d0 = (const float*)&Ksh[1][0];
    const float* d1 = (const float*)&VTsh[1][0];
    const int base = (wq*64 + lane) * 16;
    #pragma unroll
    for (int dsu = 0; dsu < 8; ++dsu) {
      const f32x4 a1v = (dsu < 4) ? *(const f32x4*)&d0[base + dsu*4]
                                  : *(const f32x4*)&d1[base + (dsu-4)*4];
      #pragma unroll
      for (int i = 0; i < 4; ++i) {
        const int qrow = qb + wq*16 + 4*g + i;
        const int d = dsu*16 + q16;
        const float s = seqB[(size_t)qrow * DDIM + d];
        const float av = acc[dsu][i] * f0r[i] + a1v[i] * f1r[i];
        outB[(size_t)qrow * DDIM + d] = 0.5f * s * (1.f + av);
      }
    }
  }
}

extern "C" void kernel_launch(void* const* d_in, const int* in_sizes, int n_in,
                              void* d_out, int out_size, void* d_ws, size_t ws_size,
                              hipStream_t stream) {
  const float* seq  = (const float*)d_in[0];
  const float* fism = (const float*)d_in[1];
  float* out = (float*)d_out;
  gattn<<<dim3(256), dim3(512), 0, stream>>>(seq, fism, out);
}